// Round 4
// baseline (489.672 us; speedup 1.0000x reference)
//
#include <hip/hip_runtime.h>

#define N_NEURONS   100000
#define INPUT_SIZE  1024
#define OUTPUT_SIZE 256
#define E_SYN       10000000
#define STEPS       3

#define RANGES      8
#define BIN         12500          // neurons per range; RANGES*BIN == N_NEURONS
#define SCAT_BLK    1024           // 2 blocks/CU -> 32 waves/CU
#define CBLK        64             // blocks per range in scatter
#define RG          8              // reduce groups (fixed association)
#define RSL         (CBLK / RG)    // 8 slabs per group
#define CAP         1280000        // per-range bucket capacity
#define VEC4        (E_SYN / 4)

// pass-A partition geometry (one wave per chunk, no LDS) -- round-2 verbatim
#define CHK         1024                 // edges per chunk
#define NCH         9766                 // ceil(E_SYN / CHK)
#define PITER       (CHK / 256)          // 4 int4 iterations per wave
#define PW          4                    // waves (chunks) per 256-thr block
#define HIST_GRID   ((NCH + PW - 1) / PW)
#define PART_GRID   ((NCH + PW - 1) / PW)
#define SCJ         ((NCH + 1023) / 1024)   // scan items per thread (10)

// pass-B sub-sort geometry: order each range bucket by src-subrange
#define NSB         32                   // src sub-ranges (window 3125*4B = 12.5KB)
#define SBW         (N_NEURONS / NSB)    // 3125
#define JB          (CAP / 2048)         // 625 record-chunks per range
#define B_GRID      ((RANGES * JB + 3) / 4)

// v init
__global__ void init_state(const float* __restrict__ x, float* __restrict__ v) {
    int i = blockIdx.x * blockDim.x + threadIdx.x;
    if (i < N_NEURONS) v[i] = (i < INPUT_SIZE) ? x[i] : 0.0f;
}

// ---- pass A (round-2 verbatim): 8 dst-range buckets, ballot-rank, coalesced ----
__global__ __launch_bounds__(256) void hist_kernel(const int* __restrict__ dst,
                                                   int* __restrict__ hist) {
    const int lane  = threadIdx.x & 63;
    const int wv    = threadIdx.x >> 6;
    const int chunk = blockIdx.x * PW + wv;
    if (chunk >= NCH) return;
    const int beg = chunk * CHK;
    const int4* dst4 = (const int4*)dst;
    int h = 0;
    for (int it = 0; it < PITER; ++it) {
        int e   = beg + (it * 64 + lane) * 4;
        bool ok = (e < E_SYN);
        int4 d4 = ok ? dst4[e >> 2] : make_int4(0, 0, 0, 0);
        unsigned long long okm = __ballot(ok);
        int rk[4] = {d4.x / BIN, d4.y / BIN, d4.z / BIN, d4.w / BIN};
#pragma unroll
        for (int k = 0; k < 4; ++k) {
            unsigned long long b0 = __ballot(rk[k] & 1);
            unsigned long long b1 = __ballot(rk[k] & 2);
            unsigned long long b2 = __ballot(rk[k] & 4);
            unsigned long long m = ((lane & 1) ? b0 : ~b0) &
                                   ((lane & 2) ? b1 : ~b1) &
                                   ((lane & 4) ? b2 : ~b2) & okm;
            h += __popcll(m);
        }
    }
    if (lane < RANGES) hist[(size_t)lane * NCH + chunk] = h;
}

__global__ __launch_bounds__(1024) void scan_kernel(const int* __restrict__ hist,
                                                    int* __restrict__ bases,
                                                    int* __restrict__ gcur) {
    const int r = blockIdx.x;
    const int t = threadIdx.x;
    const int lane = t & 63;
    const int wv   = t >> 6;
    int vals[SCJ];
    int s = 0;
#pragma unroll
    for (int j = 0; j < SCJ; ++j) {
        int idx = t * SCJ + j;
        int vv  = (idx < NCH) ? hist[(size_t)r * NCH + idx] : 0;
        vals[j] = vv;
        s += vv;
    }
    int x = s;
#pragma unroll
    for (int d = 1; d < 64; d <<= 1) {
        int y = __shfl_up(x, d, 64);
        if (lane >= d) x += y;
    }
    __shared__ int wsum[16];
    if (lane == 63) wsum[wv] = x;
    __syncthreads();
    if (wv == 0) {
        int y = (lane < 16) ? wsum[lane] : 0;
        int z = y;
#pragma unroll
        for (int d = 1; d < 16; d <<= 1) {
            int u = __shfl_up(z, d, 64);
            if (lane >= d) z += u;
        }
        if (lane < 16) wsum[lane] = z - y;
    }
    __syncthreads();
    int run = (x - s) + wsum[wv];
#pragma unroll
    for (int j = 0; j < SCJ; ++j) {
        int idx = t * SCJ + j;
        if (idx < NCH) bases[(size_t)r * NCH + idx] = r * CAP + run;
        run += vals[j];
    }
    if (t == 1023) gcur[r] = run;
}

__global__ __launch_bounds__(256) void partition_kernel(
        const float* __restrict__ w,
        const int*   __restrict__ src,
        const int*   __restrict__ dst,
        const int*   __restrict__ bases,
        int2* __restrict__ recs) {
    const int lane  = threadIdx.x & 63;
    const int wv    = threadIdx.x >> 6;
    const int chunk = blockIdx.x * PW + wv;
    if (chunk >= NCH) return;
    const unsigned long long ltmask = (1ull << lane) - 1ull;

    int cur = 0;                              // lane r holds range r's cursor
    if (lane < RANGES) cur = bases[(size_t)lane * NCH + chunk];

    const int beg = chunk * CHK;
    const int4* dst4 = (const int4*)dst;
    const int4* src4 = (const int4*)src;
    const int4* wq4  = (const int4*)w;

    for (int it = 0; it < PITER; ++it) {
        int e   = beg + (it * 64 + lane) * 4;
        bool ok = (e < E_SYN);
        int idx = e >> 2;
        int4 d4 = ok ? dst4[idx] : make_int4(0, 0, 0, 0);
        int4 s4 = ok ? src4[idx] : make_int4(0, 0, 0, 0);
        int4 q4 = ok ? wq4[idx]  : make_int4(0, 0, 0, 0);
        unsigned long long okm = __ballot(ok);
        int dd[4] = {d4.x, d4.y, d4.z, d4.w};
        int ss[4] = {s4.x, s4.y, s4.z, s4.w};
        int qq[4] = {q4.x, q4.y, q4.z, q4.w};
#pragma unroll
        for (int k = 0; k < 4; ++k) {
            int d = dd[k];
            int r = d / BIN;
            unsigned long long b0 = __ballot(r & 1);
            unsigned long long b1 = __ballot(r & 2);
            unsigned long long b2 = __ballot(r & 4);
            unsigned long long mym = ((r & 1) ? b0 : ~b0) &
                                     ((r & 2) ? b1 : ~b1) &
                                     ((r & 4) ? b2 : ~b2) & okm;
            int rank = __popcll(mym & ltmask);
            int gpos = __shfl(cur, r, 64) + rank;
            if (ok) recs[(size_t)gpos] =
                make_int2((ss[k] << 14) | (d - r * BIN), qq[k]);
            unsigned long long mm = ((lane & 1) ? b0 : ~b0) &
                                    ((lane & 2) ? b1 : ~b1) &
                                    ((lane & 4) ? b2 : ~b2) & okm;
            cur += __popcll(mm);
        }
    }
}

// ---- pass B: sub-sort each range bucket by src-subrange (NSB=32) ----

// 32-sb histogram per fixed 2048-record chunk of each bucket (ballot counting).
__global__ __launch_bounds__(256) void histB_kernel(const int2* __restrict__ recs,
                                                    const int*  __restrict__ gcur,
                                                    int* __restrict__ histB) {
    const int lane = threadIdx.x & 63;
    const int wv   = threadIdx.x >> 6;
    const int gid  = blockIdx.x * 4 + wv;
    if (gid >= RANGES * JB) return;
    const int r = gid / JB;
    const int j = gid - r * JB;
    const int cnt = gcur[r];
    const int2* rb = recs + (size_t)r * CAP;
    const int base = j * 2048;
    int h = 0;
    const int c = lane & 31;
    for (int it = 0; it < 32; ++it) {
        int idx = base + it * 64 + lane;
        bool ok = idx < cnt;
        int rx  = ok ? rb[idx].x : 0;
        int sb  = (rx >> 14) / SBW;
        unsigned long long okm = __ballot(ok);
        unsigned long long b0 = __ballot(sb & 1);
        unsigned long long b1 = __ballot(sb & 2);
        unsigned long long b2 = __ballot(sb & 4);
        unsigned long long b3 = __ballot(sb & 8);
        unsigned long long b4 = __ballot(sb & 16);
        unsigned long long m = ((c & 1) ? b0 : ~b0) & ((c & 2) ? b1 : ~b1) &
                               ((c & 4) ? b2 : ~b2) & ((c & 8) ? b3 : ~b3) &
                               ((c & 16) ? b4 : ~b4) & okm;
        h += __popcll(m);
    }
    if (lane < NSB) histB[(size_t)(r * NSB + lane) * JB + j] = h;
}

// Per-cat (256) exclusive scan over 625 chunk counts; one wave per cat.
__global__ __launch_bounds__(64) void scanB_kernel(const int* __restrict__ histB,
                                                   int* __restrict__ basesB,
                                                   int* __restrict__ totB) {
    const int cat  = blockIdx.x;
    const int lane = threadIdx.x;
    int vals[10];
    int s = 0;
#pragma unroll
    for (int j = 0; j < 10; ++j) {
        int idx = lane * 10 + j;
        int vv  = (idx < JB) ? histB[(size_t)cat * JB + idx] : 0;
        vals[j] = vv;
        s += vv;
    }
    int x = s;
#pragma unroll
    for (int d = 1; d < 64; d <<= 1) {
        int y = __shfl_up(x, d, 64);
        if (lane >= d) x += y;
    }
    int run = x - s;
#pragma unroll
    for (int j = 0; j < 10; ++j) {
        int idx = lane * 10 + j;
        if (idx < JB) basesB[(size_t)cat * JB + idx] = run;
        run += vals[j];
    }
    if (lane == 63) totB[cat] = x;
}

// Absolute sub-bucket starts (packed, contiguous within each range bucket).
__global__ void composeB_kernel(const int* __restrict__ totB,
                                int* __restrict__ gstartB) {
    int r = threadIdx.x;
    if (r < RANGES) {
        int s = r * CAP;
        for (int sb = 0; sb < NSB; ++sb) {
            gstartB[r * NSB + sb] = s;
            s += totB[r * NSB + sb];
        }
    }
}

// Re-scatter records into src-subrange order. One wave per 2048-record chunk;
// lane c<32 owns cat c's cursor; 2 records per lane per step (int4 load).
__global__ __launch_bounds__(256) void partB_kernel(const int2* __restrict__ recs,
                                                    const int*  __restrict__ gcur,
                                                    const int*  __restrict__ basesB,
                                                    const int*  __restrict__ gstartB,
                                                    int2* __restrict__ recs2) {
    const int lane = threadIdx.x & 63;
    const int wv   = threadIdx.x >> 6;
    const int gid  = blockIdx.x * 4 + wv;
    if (gid >= RANGES * JB) return;
    const int r = gid / JB;
    const int j = gid - r * JB;
    const int cnt = gcur[r];
    if (j * 2048 >= cnt) return;
    const unsigned long long ltmask = (1ull << lane) - 1ull;
    int cur = 0;
    if (lane < NSB)
        cur = gstartB[r * NSB + lane] + basesB[(size_t)(r * NSB + lane) * JB + j];
    const int4* rb4 = (const int4*)(recs + (size_t)r * CAP + (size_t)j * 2048);
    for (int it = 0; it < 16; ++it) {
        int pi  = it * 64 + lane;          // pair index within chunk (<1024)
        int idx = j * 2048 + pi * 2;
        int4 p  = rb4[pi];                 // always within CAP allocation
#pragma unroll
        for (int k = 0; k < 2; ++k) {
            bool ok = (idx + k) < cnt;
            int rx = k ? p.z : p.x;
            int ry = k ? p.w : p.y;
            int sb = (rx >> 14) / SBW;
            unsigned long long okm = __ballot(ok);
            unsigned long long b0 = __ballot(sb & 1);
            unsigned long long b1 = __ballot(sb & 2);
            unsigned long long b2 = __ballot(sb & 4);
            unsigned long long b3 = __ballot(sb & 8);
            unsigned long long b4 = __ballot(sb & 16);
            unsigned long long mym = ((sb & 1) ? b0 : ~b0) & ((sb & 2) ? b1 : ~b1) &
                                     ((sb & 4) ? b2 : ~b2) & ((sb & 8) ? b3 : ~b3) &
                                     ((sb & 16) ? b4 : ~b4) & okm;
            int rank = __popcll(mym & ltmask);
            int gpos = __shfl(cur, sb, 64) + rank;
            if (ok) recs2[(size_t)gpos] = make_int2(rx, ry);
            const int c = lane & 31;
            unsigned long long mm = ((c & 1) ? b0 : ~b0) & ((c & 2) ? b1 : ~b1) &
                                    ((c & 4) ? b2 : ~b2) & ((c & 8) ? b3 : ~b3) &
                                    ((c & 16) ? b4 : ~b4) & okm;
            if (lane < NSB) cur += __popcll(mm);
        }
    }
}

// ---- per-step kernels (round-2 verbatim) ----
__global__ __launch_bounds__(SCAT_BLK) void scatter_sorted(
        const int2* __restrict__ recs,
        const int*  __restrict__ gcur,
        const float* __restrict__ v,
        float* __restrict__ partials) {
    __shared__ float bins[BIN];
    const int r = blockIdx.x / CBLK;
    const int c = blockIdx.x % CBLK;
    for (int j = threadIdx.x; j < BIN; j += SCAT_BLK) bins[j] = 0.0f;
    __syncthreads();

    const int cnt   = gcur[r];
    const int npair = cnt >> 1;
    const int4* base4 = (const int4*)(recs + (size_t)r * CAP);
    const int stride = CBLK * SCAT_BLK;
    int u = c * SCAT_BLK + threadIdx.x;
    for (; u + 3 * stride < npair; u += 4 * stride) {
        int4 a = base4[u];
        int4 b = base4[u + stride];
        int4 e = base4[u + 2 * stride];
        int4 f = base4[u + 3 * stride];
        float va0 = v[a.x >> 14];
        float va1 = v[a.z >> 14];
        float vb0 = v[b.x >> 14];
        float vb1 = v[b.z >> 14];
        float ve0 = v[e.x >> 14];
        float ve1 = v[e.z >> 14];
        float vf0 = v[f.x >> 14];
        float vf1 = v[f.z >> 14];
        atomicAdd(&bins[a.x & 16383], va0 * __int_as_float(a.y));
        atomicAdd(&bins[a.z & 16383], va1 * __int_as_float(a.w));
        atomicAdd(&bins[b.x & 16383], vb0 * __int_as_float(b.y));
        atomicAdd(&bins[b.z & 16383], vb1 * __int_as_float(b.w));
        atomicAdd(&bins[e.x & 16383], ve0 * __int_as_float(e.y));
        atomicAdd(&bins[e.z & 16383], ve1 * __int_as_float(e.w));
        atomicAdd(&bins[f.x & 16383], vf0 * __int_as_float(f.y));
        atomicAdd(&bins[f.z & 16383], vf1 * __int_as_float(f.w));
    }
    for (; u < npair; u += stride) {
        int4 a = base4[u];
        atomicAdd(&bins[a.x & 16383], v[a.x >> 14] * __int_as_float(a.y));
        atomicAdd(&bins[a.z & 16383], v[a.z >> 14] * __int_as_float(a.w));
    }
    if ((cnt & 1) && c == 0 && threadIdx.x == 0) {
        int2 p = recs[(size_t)r * CAP + cnt - 1];
        atomicAdd(&bins[p.x & 16383], v[p.x >> 14] * __int_as_float(p.y));
    }
    __syncthreads();
    float* o = partials + (size_t)(r * CBLK + c) * BIN;
    for (int j = threadIdx.x; j < BIN; j += SCAT_BLK) o[j] = bins[j];
}

__global__ void reduce_fused(const float* __restrict__ partials,
                             const float* __restrict__ bias,
                             float* __restrict__ v,
                             float* __restrict__ out,
                             int write_out) {
    int i4 = 4 * (blockIdx.x * blockDim.x + threadIdx.x);
    if (i4 >= N_NEURONS) return;
    const int r = i4 / BIN;
    const int j = i4 - r * BIN;
    const float* base = partials + (size_t)(r * CBLK) * BIN + j;
    float4 tot = {0.f, 0.f, 0.f, 0.f};
#pragma unroll 2
    for (int g = 0; g < RG; ++g) {
        float4 a = {0.f, 0.f, 0.f, 0.f};
#pragma unroll
        for (int cc = 0; cc < RSL; ++cc) {
            float4 p = *(const float4*)(base + (size_t)(g * RSL + cc) * BIN);
            a.x += p.x; a.y += p.y; a.z += p.z; a.w += p.w;
        }
        tot.x += a.x; tot.y += a.y; tot.z += a.z; tot.w += a.w;
    }
    float av[4] = {tot.x, tot.y, tot.z, tot.w};
#pragma unroll
    for (int k = 0; k < 4; ++k) {
        int i = i4 + k;
        float val = av[k] + ((i >= INPUT_SIZE) ? bias[i - INPUT_SIZE] : 0.0f);
        float nv  = (i < N_NEURONS - OUTPUT_SIZE) ? tanhf(val) : val;
        v[i] = nv;
        if (write_out && i >= N_NEURONS - OUTPUT_SIZE)
            out[i - (N_NEURONS - OUTPUT_SIZE)] = val;
    }
}

// ---- fallback (small ws): multi-pass binned rescan path ----
__global__ void scatter_binned(const float* __restrict__ w,
                               const int*   __restrict__ src,
                               const int*   __restrict__ dst,
                               const float* __restrict__ v,
                               float*       __restrict__ partials,
                               int C) {
    __shared__ float bins[BIN];
    const int r = blockIdx.x / C;
    const int c = blockIdx.x % C;
    const int lo = r * BIN;
    const int hi = lo + BIN;
    for (int j = threadIdx.x; j < BIN; j += blockDim.x) bins[j] = 0.0f;
    __syncthreads();
    const int4*   src4 = (const int4*)src;
    const int4*   dst4 = (const int4*)dst;
    const float4* w4v  = (const float4*)w;
    const int stride = C * blockDim.x;
    for (int u = c * blockDim.x + threadIdx.x; u < VEC4; u += stride) {
        const int4   s4 = src4[u];
        const int4   d4 = dst4[u];
        const float4 wv = w4v[u];
        int   s[4] = {s4.x, s4.y, s4.z, s4.w};
        int   d[4] = {d4.x, d4.y, d4.z, d4.w};
        float ww[4] = {wv.x, wv.y, wv.z, wv.w};
#pragma unroll
        for (int k = 0; k < 4; ++k)
            if (d[k] >= lo && d[k] < hi)
                atomicAdd(&bins[d[k] - lo], v[s[k]] * ww[k]);
    }
    __syncthreads();
    float* o = partials + ((size_t)(r * C + c)) * BIN;
    for (int j = threadIdx.x; j < BIN; j += blockDim.x) o[j] = bins[j];
}
__global__ void reduce_update_fb(const float* __restrict__ partials,
                                 const float* __restrict__ bias,
                                 float* __restrict__ v,
                                 float* __restrict__ out,
                                 int C, int write_out) {
    int i4 = 4 * (blockIdx.x * blockDim.x + threadIdx.x);
    if (i4 >= N_NEURONS) return;
    const int r = i4 / BIN;
    const int j = i4 - r * BIN;
    const float* base = partials + ((size_t)r * C) * BIN + j;
    float4 acc = {0.f, 0.f, 0.f, 0.f};
    for (int c = 0; c < C; ++c) {
        float4 p = *(const float4*)(base + (size_t)c * BIN);
        acc.x += p.x; acc.y += p.y; acc.z += p.z; acc.w += p.w;
    }
    float av[4] = {acc.x, acc.y, acc.z, acc.w};
#pragma unroll
    for (int k = 0; k < 4; ++k) {
        int i = i4 + k;
        float val = av[k] + ((i >= INPUT_SIZE) ? bias[i - INPUT_SIZE] : 0.0f);
        float nv  = (i < N_NEURONS - OUTPUT_SIZE) ? tanhf(val) : val;
        v[i] = nv;
        if (write_out && i >= N_NEURONS - OUTPUT_SIZE)
            out[i - (N_NEURONS - OUTPUT_SIZE)] = val;
    }
}

extern "C" void kernel_launch(void* const* d_in, const int* in_sizes, int n_in,
                              void* d_out, int out_size, void* d_ws, size_t ws_size,
                              hipStream_t stream) {
    const float* x    = (const float*)d_in[0];
    const float* w    = (const float*)d_in[1];
    const float* bias = (const float*)d_in[2];
    const int*   src  = (const int*)d_in[3];
    const int*   dst  = (const int*)d_in[4];
    float* out = (float*)d_out;

    const int blk = 256;
    const int grid_n   = (N_NEURONS + blk - 1) / blk;
    const int red_grid = (N_NEURONS / 4 + blk - 1) / blk;

    // ws layout: v | partials | histA | basesA | histB | basesB | totB |
    //            gstartB | gcur | recs | recs2
    float* v        = (float*)d_ws;
    float* partials = v + N_NEURONS;
    int*   histA    = (int*)(partials + (size_t)RANGES * CBLK * BIN);
    int*   basesA   = histA + (size_t)RANGES * NCH;
    int*   histB    = basesA + (size_t)RANGES * NCH;
    int*   basesB   = histB + (size_t)RANGES * NSB * JB;
    int*   totB     = basesB + (size_t)RANGES * NSB * JB;
    int*   gstartB  = totB + RANGES * NSB;
    int*   gcur     = gstartB + RANGES * NSB;
    int2*  recs     = (int2*)(gcur + RANGES);
    int2*  recs2    = recs + (size_t)RANGES * CAP;
    size_t need_sorted = (size_t)((char*)recs2 - (char*)d_ws);
    size_t need_full   = (size_t)((char*)(recs2 + (size_t)RANGES * CAP) - (char*)d_ws);

    if (ws_size >= need_sorted) {
        const bool subsort = (ws_size >= need_full);
        init_state<<<grid_n, blk, 0, stream>>>(x, v);
        hist_kernel<<<HIST_GRID, 256, 0, stream>>>(dst, histA);
        scan_kernel<<<RANGES, 1024, 0, stream>>>(histA, basesA, gcur);
        partition_kernel<<<PART_GRID, 256, 0, stream>>>(w, src, dst, basesA, recs);
        const int2* srecs = recs;
        if (subsort) {
            histB_kernel<<<B_GRID, 256, 0, stream>>>(recs, gcur, histB);
            scanB_kernel<<<RANGES * NSB, 64, 0, stream>>>(histB, basesB, totB);
            composeB_kernel<<<1, 64, 0, stream>>>(totB, gstartB);
            partB_kernel<<<B_GRID, 256, 0, stream>>>(recs, gcur, basesB, gstartB, recs2);
            srecs = recs2;
        }
        for (int s = 0; s < STEPS; ++s) {
            scatter_sorted<<<RANGES * CBLK, SCAT_BLK, 0, stream>>>(
                srecs, gcur, v, partials);
            reduce_fused<<<red_grid, blk, 0, stream>>>(
                partials, bias, v, out, s == STEPS - 1 ? 1 : 0);
        }
    } else {
        long C = (long)(ws_size / 4 / N_NEURONS) - 1;
        if (C > 64) C = 64;
        if (C < 1) C = 1;
        float* part_fb = v + N_NEURONS;
        init_state<<<grid_n, blk, 0, stream>>>(x, v);
        for (int s = 0; s < STEPS; ++s) {
            scatter_binned<<<RANGES * (int)C, SCAT_BLK, 0, stream>>>(
                w, src, dst, v, part_fb, (int)C);
            reduce_update_fb<<<red_grid, blk, 0, stream>>>(
                part_fb, bias, v, out, (int)C, s == STEPS - 1 ? 1 : 0);
        }
    }
}

// Round 5
// 471.593 us; speedup vs baseline: 1.0383x; 1.0383x over previous
//
#include <hip/hip_runtime.h>

#define N_NEURONS   100000
#define INPUT_SIZE  1024
#define OUTPUT_SIZE 256
#define E_SYN       10000000
#define STEPS       3

#define RANGES      8
#define BIN         12500          // neurons per range; RANGES*BIN == N_NEURONS
#define SCAT_BLK    1024
#define CBLK        64             // blocks per range in scatter
#define RG          8              // reduce groups (fixed association)
#define RSL         (CBLK / RG)    // 8 slabs per group
#define CAP         1280000        // per-range bucket capacity
#define VEC4        (E_SYN / 4)

// pass-A partition geometry (one wave per chunk, no LDS) -- round-2 verbatim
#define CHK         1024                 // edges per chunk
#define NCH         9766                 // ceil(E_SYN / CHK)
#define PITER       (CHK / 256)          // 4 int4 iterations per wave
#define PW          4                    // waves (chunks) per 256-thr block
#define HIST_GRID   ((NCH + PW - 1) / PW)
#define PART_GRID   ((NCH + PW - 1) / PW)
#define SCJ         ((NCH + 1023) / 1024)   // scan items per thread (10)

// pass-B sub-sort: order each range bucket by src-window (NSB windows)
#define NSB         16                   // src windows; window = 6250 fl = 25KB
#define SBW         (N_NEURONS / NSB)    // 6250
#define RCHK        2048                 // records per pass-B chunk
#define JB          (CAP / RCHK)         // 625 chunks per range
#define NCHB        (RANGES * JB)        // 5000 total chunks
#define HB_GRID     ((NCHB + 3) / 4)
#define PB_GRID     ((NCHB + 1) / 2)

// v init
__global__ void init_state(const float* __restrict__ x, float* __restrict__ v) {
    int i = blockIdx.x * blockDim.x + threadIdx.x;
    if (i < N_NEURONS) v[i] = (i < INPUT_SIZE) ? x[i] : 0.0f;
}

// ---- pass A (round-2 verbatim): 8 dst-range buckets, ballot-rank, coalesced ----
__global__ __launch_bounds__(256) void hist_kernel(const int* __restrict__ dst,
                                                   int* __restrict__ hist) {
    const int lane  = threadIdx.x & 63;
    const int wv    = threadIdx.x >> 6;
    const int chunk = blockIdx.x * PW + wv;
    if (chunk >= NCH) return;
    const int beg = chunk * CHK;
    const int4* dst4 = (const int4*)dst;
    int h = 0;
    for (int it = 0; it < PITER; ++it) {
        int e   = beg + (it * 64 + lane) * 4;
        bool ok = (e < E_SYN);
        int4 d4 = ok ? dst4[e >> 2] : make_int4(0, 0, 0, 0);
        unsigned long long okm = __ballot(ok);
        int rk[4] = {d4.x / BIN, d4.y / BIN, d4.z / BIN, d4.w / BIN};
#pragma unroll
        for (int k = 0; k < 4; ++k) {
            unsigned long long b0 = __ballot(rk[k] & 1);
            unsigned long long b1 = __ballot(rk[k] & 2);
            unsigned long long b2 = __ballot(rk[k] & 4);
            unsigned long long m = ((lane & 1) ? b0 : ~b0) &
                                   ((lane & 2) ? b1 : ~b1) &
                                   ((lane & 4) ? b2 : ~b2) & okm;
            h += __popcll(m);
        }
    }
    if (lane < RANGES) hist[(size_t)lane * NCH + chunk] = h;
}

__global__ __launch_bounds__(1024) void scan_kernel(const int* __restrict__ hist,
                                                    int* __restrict__ bases,
                                                    int* __restrict__ gcur) {
    const int r = blockIdx.x;
    const int t = threadIdx.x;
    const int lane = t & 63;
    const int wv   = t >> 6;
    int vals[SCJ];
    int s = 0;
#pragma unroll
    for (int j = 0; j < SCJ; ++j) {
        int idx = t * SCJ + j;
        int vv  = (idx < NCH) ? hist[(size_t)r * NCH + idx] : 0;
        vals[j] = vv;
        s += vv;
    }
    int x = s;
#pragma unroll
    for (int d = 1; d < 64; d <<= 1) {
        int y = __shfl_up(x, d, 64);
        if (lane >= d) x += y;
    }
    __shared__ int wsum[16];
    if (lane == 63) wsum[wv] = x;
    __syncthreads();
    if (wv == 0) {
        int y = (lane < 16) ? wsum[lane] : 0;
        int z = y;
#pragma unroll
        for (int d = 1; d < 16; d <<= 1) {
            int u = __shfl_up(z, d, 64);
            if (lane >= d) z += u;
        }
        if (lane < 16) wsum[lane] = z - y;
    }
    __syncthreads();
    int run = (x - s) + wsum[wv];
#pragma unroll
    for (int j = 0; j < SCJ; ++j) {
        int idx = t * SCJ + j;
        if (idx < NCH) bases[(size_t)r * NCH + idx] = r * CAP + run;
        run += vals[j];
    }
    if (t == 1023) gcur[r] = run;
}

__global__ __launch_bounds__(256) void partition_kernel(
        const float* __restrict__ w,
        const int*   __restrict__ src,
        const int*   __restrict__ dst,
        const int*   __restrict__ bases,
        int2* __restrict__ recs) {
    const int lane  = threadIdx.x & 63;
    const int wv    = threadIdx.x >> 6;
    const int chunk = blockIdx.x * PW + wv;
    if (chunk >= NCH) return;
    const unsigned long long ltmask = (1ull << lane) - 1ull;

    int cur = 0;                              // lane r holds range r's cursor
    if (lane < RANGES) cur = bases[(size_t)lane * NCH + chunk];

    const int beg = chunk * CHK;
    const int4* dst4 = (const int4*)dst;
    const int4* src4 = (const int4*)src;
    const int4* wq4  = (const int4*)w;

    for (int it = 0; it < PITER; ++it) {
        int e   = beg + (it * 64 + lane) * 4;
        bool ok = (e < E_SYN);
        int idx = e >> 2;
        int4 d4 = ok ? dst4[idx] : make_int4(0, 0, 0, 0);
        int4 s4 = ok ? src4[idx] : make_int4(0, 0, 0, 0);
        int4 q4 = ok ? wq4[idx]  : make_int4(0, 0, 0, 0);
        unsigned long long okm = __ballot(ok);
        int dd[4] = {d4.x, d4.y, d4.z, d4.w};
        int ss[4] = {s4.x, s4.y, s4.z, s4.w};
        int qq[4] = {q4.x, q4.y, q4.z, q4.w};
#pragma unroll
        for (int k = 0; k < 4; ++k) {
            int d = dd[k];
            int r = d / BIN;
            unsigned long long b0 = __ballot(r & 1);
            unsigned long long b1 = __ballot(r & 2);
            unsigned long long b2 = __ballot(r & 4);
            unsigned long long mym = ((r & 1) ? b0 : ~b0) &
                                     ((r & 2) ? b1 : ~b1) &
                                     ((r & 4) ? b2 : ~b2) & okm;
            int rank = __popcll(mym & ltmask);
            int gpos = __shfl(cur, r, 64) + rank;
            if (ok) recs[(size_t)gpos] =
                make_int2((ss[k] << 14) | (d - r * BIN), qq[k]);
            unsigned long long mm = ((lane & 1) ? b0 : ~b0) &
                                    ((lane & 2) ? b1 : ~b1) &
                                    ((lane & 4) ? b2 : ~b2) & okm;
            cur += __popcll(mm);
        }
    }
}

// ---- pass B: sub-sort each range bucket by src-window (16 cats) ----

// Per-chunk 16-window histogram (ballot counting, lanes<16 own cats).
__global__ __launch_bounds__(256) void histB_kernel(const int2* __restrict__ recs,
                                                    const int*  __restrict__ gcur,
                                                    int* __restrict__ histB) {
    const int lane = threadIdx.x & 63;
    const int wv   = threadIdx.x >> 6;
    const int gid  = blockIdx.x * 4 + wv;
    if (gid >= NCHB) return;
    const int r = gid / JB;
    const int j = gid - r * JB;
    const int cnt = gcur[r];
    if (j * RCHK >= cnt) { if (lane < NSB) histB[(size_t)(r * NSB + lane) * JB + j] = 0; return; }
    const int2* rb = recs + (size_t)r * CAP;
    const int base = j * RCHK;
    int h = 0;
    const int c = lane & 15;
    for (int it = 0; it < RCHK / 64; ++it) {
        int idx = base + it * 64 + lane;
        bool ok = idx < cnt;
        int rx  = ok ? rb[idx].x : 0;
        int sb  = (rx >> 14) / SBW;
        unsigned long long okm = __ballot(ok);
        unsigned long long b0 = __ballot(sb & 1);
        unsigned long long b1 = __ballot(sb & 2);
        unsigned long long b2 = __ballot(sb & 4);
        unsigned long long b3 = __ballot(sb & 8);
        unsigned long long m = ((c & 1) ? b0 : ~b0) & ((c & 2) ? b1 : ~b1) &
                               ((c & 4) ? b2 : ~b2) & ((c & 8) ? b3 : ~b3) & okm;
        h += __popcll(m);
    }
    if (lane < NSB) histB[(size_t)(r * NSB + lane) * JB + j] = h;
}

// Per-cat (128) exclusive scan over 625 chunk counts; one wave per cat.
__global__ __launch_bounds__(64) void scanB_kernel(const int* __restrict__ histB,
                                                   int* __restrict__ basesB,
                                                   int* __restrict__ totB) {
    const int cat  = blockIdx.x;
    const int lane = threadIdx.x;
    int vals[10];
    int s = 0;
#pragma unroll
    for (int j = 0; j < 10; ++j) {
        int idx = lane * 10 + j;
        int vv  = (idx < JB) ? histB[(size_t)cat * JB + idx] : 0;
        vals[j] = vv;
        s += vv;
    }
    int x = s;
#pragma unroll
    for (int d = 1; d < 64; d <<= 1) {
        int y = __shfl_up(x, d, 64);
        if (lane >= d) x += y;
    }
    int run = x - s;
#pragma unroll
    for (int j = 0; j < 10; ++j) {
        int idx = lane * 10 + j;
        if (idx < JB) basesB[(size_t)cat * JB + idx] = run;
        run += vals[j];
    }
    if (lane == 63) totB[cat] = x;
}

// Window starts (padded to even for int4 pair streaming) + ends; zero-weight
// hole records fill odd-length pads (src points into own window -> safe).
__global__ void composeB_kernel(const int* __restrict__ totB,
                                int* __restrict__ gstartB,
                                int* __restrict__ wendB,
                                int2* __restrict__ recs2) {
    const int t = threadIdx.x;
    if (t < RANGES) {
        int s = t * CAP;
        for (int sb = 0; sb < NSB; ++sb) {
            int c = t * NSB + sb;
            gstartB[c] = s;
            s += totB[c];
            s = (s + 1) & ~1;
            wendB[c] = s;
        }
    }
    __syncthreads();
    if (t < RANGES * NSB) {
        int tot = totB[t];
        if (tot & 1) {
            int sb = t & (NSB - 1);
            recs2[(size_t)gstartB[t] + tot] = make_int2((sb * SBW) << 14, 0);
        }
    }
}

// Local counting-sort per 2048-record chunk (one wave, 16KB LDS tile), then
// burst each window segment out as long coalesced runs (avg 128 recs; runs of
// consecutive chunks concatenate globally -> full-line writes, no
// fragmentation). Deterministic; no atomics, no rings.
__global__ __launch_bounds__(128) void partB_kernel(const int2* __restrict__ recs,
                                                    const int*  __restrict__ gcur,
                                                    const int*  __restrict__ histB,
                                                    const int*  __restrict__ basesB,
                                                    const int*  __restrict__ gstartB,
                                                    int2* __restrict__ recs2) {
    __shared__ int2 tile[2][RCHK];
    const int lane = threadIdx.x & 63;
    const int wv   = threadIdx.x >> 6;
    const int gid  = blockIdx.x * 2 + wv;
    if (gid >= NCHB) return;
    const int r = gid / JB;
    const int j = gid - r * JB;
    const int cnt = gcur[r];
    if (j * RCHK >= cnt) return;
    const unsigned long long ltmask = (1ull << lane) - 1ull;

    int h = 0, gd = 0;
    if (lane < NSB) {
        h  = histB[(size_t)(r * NSB + lane) * JB + j];
        gd = gstartB[r * NSB + lane] + basesB[(size_t)(r * NSB + lane) * JB + j];
    }
    // exclusive scan of h over lanes 0..15 -> local tile base
    int x = h;
#pragma unroll
    for (int d = 1; d < 16; d <<= 1) {
        int y = __shfl_up(x, d, 64);
        if (lane >= d) x += y;
    }
    const int lb = x - h;

    int2* tl = tile[wv];
    const int4* rb4 = (const int4*)(recs + (size_t)r * CAP + (size_t)j * RCHK);
    int cnt_c = 0;                       // lane c<16 owns window c's running count
    for (int it = 0; it < RCHK / 128; ++it) {
        int pi  = it * 64 + lane;
        int idx = j * RCHK + pi * 2;
        int4 p  = rb4[pi];               // within CAP allocation always
#pragma unroll
        for (int k = 0; k < 2; ++k) {
            bool ok = (idx + k) < cnt;
            int rx = k ? p.z : p.x;
            int ry = k ? p.w : p.y;
            int sb = (rx >> 14) / SBW;
            unsigned long long okm = __ballot(ok);
            unsigned long long b0 = __ballot(sb & 1);
            unsigned long long b1 = __ballot(sb & 2);
            unsigned long long b2 = __ballot(sb & 4);
            unsigned long long b3 = __ballot(sb & 8);
            unsigned long long mym = ((sb & 1) ? b0 : ~b0) & ((sb & 2) ? b1 : ~b1) &
                                     ((sb & 4) ? b2 : ~b2) & ((sb & 8) ? b3 : ~b3) & okm;
            int rank = __popcll(mym & ltmask);
            int pos  = __shfl(lb + cnt_c, sb, 64) + rank;
            if (ok) tl[pos] = make_int2(rx, ry);
            unsigned long long mm = ((lane & 1) ? b0 : ~b0) & ((lane & 2) ? b1 : ~b1) &
                                    ((lane & 4) ? b2 : ~b2) & ((lane & 8) ? b3 : ~b3) & okm;
            cnt_c += __popcll(mm);
        }
    }
    // burst out each window's local segment (coalesced 8B stores)
    for (int c = 0; c < NSB; ++c) {
        const int len = __shfl(h, c, 64);
        const int lbc = __shfl(lb, c, 64);
        const int gdc = __shfl(gd, c, 64);
        for (int off = lane; off < len; off += 64)
            recs2[(size_t)gdc + off] = tl[lbc + off];
    }
}

// Per step: block (r,c) owns a CONTIGUOUS pair-range of bucket r (sorted by
// src-window). For each overlapping window: stage 25KB v-slice into LDS, then
// stream; gather and accumulate are both LDS ops (no divergent global reads).
// LDS = 50KB bins + 25KB window = 75KB dynamic -> 2 blocks/CU = 32 waves/CU.
__global__ __launch_bounds__(SCAT_BLK) void scatter_win(
        const int2* __restrict__ recs2,
        const int*  __restrict__ gstartB,
        const int*  __restrict__ wendB,
        const float* __restrict__ v,
        float* __restrict__ partials) {
    extern __shared__ float smem[];
    float* bins = smem;            // [BIN]
    float* vst  = smem + BIN;      // [SBW]
    const int r = blockIdx.x / CBLK;
    const int c = blockIdx.x % CBLK;
    const int tid = threadIdx.x;
    for (int j = tid; j < BIN; j += SCAT_BLK) bins[j] = 0.0f;

    const int rbeg_p = (r * CAP) >> 1;
    const int rend_p = wendB[r * NSB + NSB - 1] >> 1;
    const int npair  = rend_p - rbeg_p;
    const int plo = rbeg_p + (int)((long)npair * c / CBLK);
    const int phi = rbeg_p + (int)((long)npair * (c + 1) / CBLK);
    const int4* rec4 = (const int4*)recs2;

    for (int sb = 0; sb < NSB; ++sb) {
        const int ws = gstartB[r * NSB + sb] >> 1;
        const int we = wendB[r * NSB + sb] >> 1;
        const int a = plo > ws ? plo : ws;
        const int b = phi < we ? phi : we;
        if (a >= b) continue;                   // block-uniform
        __syncthreads();                        // bins init / prior window done
        const float2* vs2 = (const float2*)(v + sb * SBW);
        float2* vt2 = (float2*)vst;
        for (int j = tid; j < SBW / 2; j += SCAT_BLK) vt2[j] = vs2[j];
        __syncthreads();
        const int sbb = sb * SBW;
        int u = a + tid;
        for (; u + SCAT_BLK < b; u += 2 * SCAT_BLK) {
            int4 p = rec4[u];
            int4 q = rec4[u + SCAT_BLK];
            float v0 = vst[(p.x >> 14) - sbb];
            float v1 = vst[(p.z >> 14) - sbb];
            float v2 = vst[(q.x >> 14) - sbb];
            float v3 = vst[(q.z >> 14) - sbb];
            atomicAdd(&bins[p.x & 16383], v0 * __int_as_float(p.y));
            atomicAdd(&bins[p.z & 16383], v1 * __int_as_float(p.w));
            atomicAdd(&bins[q.x & 16383], v2 * __int_as_float(q.y));
            atomicAdd(&bins[q.z & 16383], v3 * __int_as_float(q.w));
        }
        for (; u < b; u += SCAT_BLK) {
            int4 p = rec4[u];
            atomicAdd(&bins[p.x & 16383], vst[(p.x >> 14) - sbb] * __int_as_float(p.y));
            atomicAdd(&bins[p.z & 16383], vst[(p.z >> 14) - sbb] * __int_as_float(p.w));
        }
    }
    __syncthreads();
    float* o = partials + (size_t)(r * CBLK + c) * BIN;
    for (int j = tid; j < BIN; j += SCAT_BLK) o[j] = bins[j];
}

// Flat scatter (round-2 verbatim) for the mid-tier fallback (no recs2 space).
__global__ __launch_bounds__(SCAT_BLK) void scatter_flat(
        const int2* __restrict__ recs,
        const int*  __restrict__ gcur,
        const float* __restrict__ v,
        float* __restrict__ partials) {
    __shared__ float bins[BIN];
    const int r = blockIdx.x / CBLK;
    const int c = blockIdx.x % CBLK;
    for (int j = threadIdx.x; j < BIN; j += SCAT_BLK) bins[j] = 0.0f;
    __syncthreads();
    const int cnt   = gcur[r];
    const int npair = cnt >> 1;
    const int4* base4 = (const int4*)(recs + (size_t)r * CAP);
    const int stride = CBLK * SCAT_BLK;
    int u = c * SCAT_BLK + threadIdx.x;
    for (; u + 3 * stride < npair; u += 4 * stride) {
        int4 a = base4[u];
        int4 b = base4[u + stride];
        int4 e = base4[u + 2 * stride];
        int4 f = base4[u + 3 * stride];
        float va0 = v[a.x >> 14];
        float va1 = v[a.z >> 14];
        float vb0 = v[b.x >> 14];
        float vb1 = v[b.z >> 14];
        float ve0 = v[e.x >> 14];
        float ve1 = v[e.z >> 14];
        float vf0 = v[f.x >> 14];
        float vf1 = v[f.z >> 14];
        atomicAdd(&bins[a.x & 16383], va0 * __int_as_float(a.y));
        atomicAdd(&bins[a.z & 16383], va1 * __int_as_float(a.w));
        atomicAdd(&bins[b.x & 16383], vb0 * __int_as_float(b.y));
        atomicAdd(&bins[b.z & 16383], vb1 * __int_as_float(b.w));
        atomicAdd(&bins[e.x & 16383], ve0 * __int_as_float(e.y));
        atomicAdd(&bins[e.z & 16383], ve1 * __int_as_float(e.w));
        atomicAdd(&bins[f.x & 16383], vf0 * __int_as_float(f.y));
        atomicAdd(&bins[f.z & 16383], vf1 * __int_as_float(f.w));
    }
    for (; u < npair; u += stride) {
        int4 a = base4[u];
        atomicAdd(&bins[a.x & 16383], v[a.x >> 14] * __int_as_float(a.y));
        atomicAdd(&bins[a.z & 16383], v[a.z >> 14] * __int_as_float(a.w));
    }
    if ((cnt & 1) && c == 0 && threadIdx.x == 0) {
        int2 p = recs[(size_t)r * CAP + cnt - 1];
        atomicAdd(&bins[p.x & 16383], v[p.x >> 14] * __int_as_float(p.y));
    }
    __syncthreads();
    float* o = partials + (size_t)(r * CBLK + c) * BIN;
    for (int j = threadIdx.x; j < BIN; j += SCAT_BLK) o[j] = bins[j];
}

// Fused reduce: 64 slabs as 8 sequential groups of 8 (fixed association),
// then bias + tanh (except outputs).
__global__ void reduce_fused(const float* __restrict__ partials,
                             const float* __restrict__ bias,
                             float* __restrict__ v,
                             float* __restrict__ out,
                             int write_out) {
    int i4 = 4 * (blockIdx.x * blockDim.x + threadIdx.x);
    if (i4 >= N_NEURONS) return;
    const int r = i4 / BIN;
    const int j = i4 - r * BIN;
    const float* base = partials + (size_t)(r * CBLK) * BIN + j;
    float4 tot = {0.f, 0.f, 0.f, 0.f};
#pragma unroll 2
    for (int g = 0; g < RG; ++g) {
        float4 a = {0.f, 0.f, 0.f, 0.f};
#pragma unroll
        for (int cc = 0; cc < RSL; ++cc) {
            float4 p = *(const float4*)(base + (size_t)(g * RSL + cc) * BIN);
            a.x += p.x; a.y += p.y; a.z += p.z; a.w += p.w;
        }
        tot.x += a.x; tot.y += a.y; tot.z += a.z; tot.w += a.w;
    }
    float av[4] = {tot.x, tot.y, tot.z, tot.w};
#pragma unroll
    for (int k = 0; k < 4; ++k) {
        int i = i4 + k;
        float val = av[k] + ((i >= INPUT_SIZE) ? bias[i - INPUT_SIZE] : 0.0f);
        float nv  = (i < N_NEURONS - OUTPUT_SIZE) ? tanhf(val) : val;
        v[i] = nv;
        if (write_out && i >= N_NEURONS - OUTPUT_SIZE)
            out[i - (N_NEURONS - OUTPUT_SIZE)] = val;
    }
}

// ---- fallback (small ws): multi-pass binned rescan path ----
__global__ void scatter_binned(const float* __restrict__ w,
                               const int*   __restrict__ src,
                               const int*   __restrict__ dst,
                               const float* __restrict__ v,
                               float*       __restrict__ partials,
                               int C) {
    __shared__ float bins[BIN];
    const int r = blockIdx.x / C;
    const int c = blockIdx.x % C;
    const int lo = r * BIN;
    const int hi = lo + BIN;
    for (int j = threadIdx.x; j < BIN; j += blockDim.x) bins[j] = 0.0f;
    __syncthreads();
    const int4*   src4 = (const int4*)src;
    const int4*   dst4 = (const int4*)dst;
    const float4* w4v  = (const float4*)w;
    const int stride = C * blockDim.x;
    for (int u = c * blockDim.x + threadIdx.x; u < VEC4; u += stride) {
        const int4   s4 = src4[u];
        const int4   d4 = dst4[u];
        const float4 wv = w4v[u];
        int   s[4] = {s4.x, s4.y, s4.z, s4.w};
        int   d[4] = {d4.x, d4.y, d4.z, d4.w};
        float ww[4] = {wv.x, wv.y, wv.z, wv.w};
#pragma unroll
        for (int k = 0; k < 4; ++k)
            if (d[k] >= lo && d[k] < hi)
                atomicAdd(&bins[d[k] - lo], v[s[k]] * ww[k]);
    }
    __syncthreads();
    float* o = partials + ((size_t)(r * C + c)) * BIN;
    for (int j = threadIdx.x; j < BIN; j += blockDim.x) o[j] = bins[j];
}
__global__ void reduce_update_fb(const float* __restrict__ partials,
                                 const float* __restrict__ bias,
                                 float* __restrict__ v,
                                 float* __restrict__ out,
                                 int C, int write_out) {
    int i4 = 4 * (blockIdx.x * blockDim.x + threadIdx.x);
    if (i4 >= N_NEURONS) return;
    const int r = i4 / BIN;
    const int j = i4 - r * BIN;
    const float* base = partials + ((size_t)r * C) * BIN + j;
    float4 acc = {0.f, 0.f, 0.f, 0.f};
    for (int c = 0; c < C; ++c) {
        float4 p = *(const float4*)(base + (size_t)c * BIN);
        acc.x += p.x; acc.y += p.y; acc.z += p.z; acc.w += p.w;
    }
    float av[4] = {acc.x, acc.y, acc.z, acc.w};
#pragma unroll
    for (int k = 0; k < 4; ++k) {
        int i = i4 + k;
        float val = av[k] + ((i >= INPUT_SIZE) ? bias[i - INPUT_SIZE] : 0.0f);
        float nv  = (i < N_NEURONS - OUTPUT_SIZE) ? tanhf(val) : val;
        v[i] = nv;
        if (write_out && i >= N_NEURONS - OUTPUT_SIZE)
            out[i - (N_NEURONS - OUTPUT_SIZE)] = val;
    }
}

extern "C" void kernel_launch(void* const* d_in, const int* in_sizes, int n_in,
                              void* d_out, int out_size, void* d_ws, size_t ws_size,
                              hipStream_t stream) {
    const float* x    = (const float*)d_in[0];
    const float* w    = (const float*)d_in[1];
    const float* bias = (const float*)d_in[2];
    const int*   src  = (const int*)d_in[3];
    const int*   dst  = (const int*)d_in[4];
    float* out = (float*)d_out;

    const int blk = 256;
    const int grid_n   = (N_NEURONS + blk - 1) / blk;
    const int red_grid = (N_NEURONS / 4 + blk - 1) / blk;

    // ws layout: v | partials | histA | basesA | histB | basesB | totB |
    //            gstartB | wendB | gcur | recs | recs2
    float* v        = (float*)d_ws;
    float* partials = v + N_NEURONS;
    int*   histA    = (int*)(partials + (size_t)RANGES * CBLK * BIN);
    int*   basesA   = histA + (size_t)RANGES * NCH;
    int*   histB    = basesA + (size_t)RANGES * NCH;
    int*   basesB   = histB + (size_t)RANGES * NSB * JB;
    int*   totB     = basesB + (size_t)RANGES * NSB * JB;
    int*   gstartB  = totB + RANGES * NSB;
    int*   wendB    = gstartB + RANGES * NSB;
    int*   gcur     = wendB + RANGES * NSB;
    int2*  recs     = (int2*)(gcur + RANGES);
    int2*  recs2    = recs + (size_t)RANGES * CAP;
    size_t need_sorted = (size_t)((char*)recs2 - (char*)d_ws);
    size_t need_full   = (size_t)((char*)(recs2 + (size_t)RANGES * CAP) - (char*)d_ws);

    if (ws_size >= need_sorted) {
        const bool subsort = (ws_size >= need_full);
        init_state<<<grid_n, blk, 0, stream>>>(x, v);
        hist_kernel<<<HIST_GRID, 256, 0, stream>>>(dst, histA);
        scan_kernel<<<RANGES, 1024, 0, stream>>>(histA, basesA, gcur);
        partition_kernel<<<PART_GRID, 256, 0, stream>>>(w, src, dst, basesA, recs);
        if (subsort) {
            static int attr_set = 0;
            if (!attr_set) {
                hipFuncSetAttribute((const void*)scatter_win,
                                    hipFuncAttributeMaxDynamicSharedMemorySize,
                                    (BIN + SBW) * (int)sizeof(float));
                attr_set = 1;
            }
            histB_kernel<<<HB_GRID, 256, 0, stream>>>(recs, gcur, histB);
            scanB_kernel<<<RANGES * NSB, 64, 0, stream>>>(histB, basesB, totB);
            composeB_kernel<<<1, 128, 0, stream>>>(totB, gstartB, wendB, recs2);
            partB_kernel<<<PB_GRID, 128, 0, stream>>>(recs, gcur, histB, basesB,
                                                      gstartB, recs2);
            for (int s = 0; s < STEPS; ++s) {
                scatter_win<<<RANGES * CBLK, SCAT_BLK,
                              (BIN + SBW) * sizeof(float), stream>>>(
                    recs2, gstartB, wendB, v, partials);
                reduce_fused<<<red_grid, blk, 0, stream>>>(
                    partials, bias, v, out, s == STEPS - 1 ? 1 : 0);
            }
        } else {
            for (int s = 0; s < STEPS; ++s) {
                scatter_flat<<<RANGES * CBLK, SCAT_BLK, 0, stream>>>(
                    recs, gcur, v, partials);
                reduce_fused<<<red_grid, blk, 0, stream>>>(
                    partials, bias, v, out, s == STEPS - 1 ? 1 : 0);
            }
        }
    } else {
        long C = (long)(ws_size / 4 / N_NEURONS) - 1;
        if (C > 64) C = 64;
        if (C < 1) C = 1;
        float* part_fb = v + N_NEURONS;
        init_state<<<grid_n, blk, 0, stream>>>(x, v);
        for (int s = 0; s < STEPS; ++s) {
            scatter_binned<<<RANGES * (int)C, SCAT_BLK, 0, stream>>>(
                w, src, dst, v, part_fb, (int)C);
            reduce_update_fb<<<red_grid, blk, 0, stream>>>(
                part_fb, bias, v, out, (int)C, s == STEPS - 1 ? 1 : 0);
        }
    }
}

// Round 7
// 397.747 us; speedup vs baseline: 1.2311x; 1.1857x over previous
//
#include <hip/hip_runtime.h>

#define N_NEURONS   100000
#define INPUT_SIZE  1024
#define OUTPUT_SIZE 256
#define E_SYN       10000000
#define STEPS       3

#define RANGES      16             // dst ranges
#define BIN         6250           // neurons per range; RANGES*BIN == N_NEURONS
#define SHIFT       13             // dst_local bits (6250 < 8192)
#define DMASK       8191
#define SCAT_BLK    512            // 4 blocks/CU (2048 thr) -> 32 waves/CU
#define CBLK        64             // blocks per range in scatter (grid 1024)
#define RG          8              // reduce groups
#define RSL         (CBLK / RG)    // 8 slabs per group
#define CAP         665600         // per-range capacity (mean 625K + ~53 sigma), even
#define VEC4        (E_SYN / 4)

// partition geometry (one wave per chunk, no LDS)
#define CHK         1024                 // edges per chunk
#define NCH         9766                 // ceil(E_SYN / CHK)
#define PITER       (CHK / 256)          // 4 int4 iterations per wave
#define PW          4                    // waves (chunks) per 256-thr block
#define HIST_GRID   ((NCH + PW - 1) / PW)
#define SCJ         ((NCH + 1023) / 1024)   // scan items per thread (10)

// 16-way category select from 4 ballot words
#define CMB(x, b0, b1, b2, b3) \
    ((((x) & 1) ? (b0) : ~(b0)) & (((x) & 2) ? (b1) : ~(b1)) & \
     (((x) & 4) ? (b2) : ~(b2)) & (((x) & 8) ? (b3) : ~(b3)))

// Per-chunk 16-range histogram (ballot counting); v-init fused in.
__global__ __launch_bounds__(256) void hist_kernel(const float* __restrict__ x,
                                                   float* __restrict__ v,
                                                   const int* __restrict__ dst,
                                                   int* __restrict__ hist) {
    const int gidx = blockIdx.x * 256 + threadIdx.x;
    if (gidx < N_NEURONS) v[gidx] = (gidx < INPUT_SIZE) ? x[gidx] : 0.0f;
    const int lane  = threadIdx.x & 63;
    const int wv    = threadIdx.x >> 6;
    const int chunk = blockIdx.x * PW + wv;
    if (chunk >= NCH) return;
    const int beg = chunk * CHK;
    const int4* dst4 = (const int4*)dst;
    int h = 0;
    for (int it = 0; it < PITER; ++it) {
        int e   = beg + (it * 64 + lane) * 4;
        bool ok = (e < E_SYN);
        int4 d4 = ok ? dst4[e >> 2] : make_int4(0, 0, 0, 0);
        unsigned long long okm = __ballot(ok);
        int rk[4] = {d4.x / BIN, d4.y / BIN, d4.z / BIN, d4.w / BIN};
#pragma unroll
        for (int k = 0; k < 4; ++k) {
            unsigned long long b0 = __ballot(rk[k] & 1);
            unsigned long long b1 = __ballot(rk[k] & 2);
            unsigned long long b2 = __ballot(rk[k] & 4);
            unsigned long long b3 = __ballot(rk[k] & 8);
            h += __popcll(CMB(lane, b0, b1, b2, b3) & okm);
        }
    }
    if (lane < RANGES) hist[(size_t)lane * NCH + chunk] = h;
}

// Per-range exclusive scan over chunk counts -> dense bases + totals.
__global__ __launch_bounds__(1024) void scan_kernel(const int* __restrict__ hist,
                                                    int* __restrict__ bases,
                                                    int* __restrict__ gcur) {
    const int r = blockIdx.x;
    const int t = threadIdx.x;
    const int lane = t & 63;
    const int wv   = t >> 6;
    int vals[SCJ];
    int s = 0;
#pragma unroll
    for (int j = 0; j < SCJ; ++j) {
        int idx = t * SCJ + j;
        int vv  = (idx < NCH) ? hist[(size_t)r * NCH + idx] : 0;
        vals[j] = vv;
        s += vv;
    }
    int x = s;
#pragma unroll
    for (int d = 1; d < 64; d <<= 1) {
        int y = __shfl_up(x, d, 64);
        if (lane >= d) x += y;
    }
    __shared__ int wsum[16];
    if (lane == 63) wsum[wv] = x;
    __syncthreads();
    if (wv == 0) {
        int y = (lane < 16) ? wsum[lane] : 0;
        int z = y;
#pragma unroll
        for (int d = 1; d < 16; d <<= 1) {
            int u = __shfl_up(z, d, 64);
            if (lane >= d) z += u;
        }
        if (lane < 16) wsum[lane] = z - y;
    }
    __syncthreads();
    int run = (x - s) + wsum[wv];
#pragma unroll
    for (int j = 0; j < SCJ; ++j) {
        int idx = t * SCJ + j;
        if (idx < NCH) bases[(size_t)r * NCH + idx] = r * CAP + run;
        run += vals[j];
    }
    if (t == 1023) gcur[r] = run;
}

// Partition into 16 range-major buckets of packed 8B records (direct scatter,
// ballot-rank, lane r<16 owns range r's cursor). Same-range lanes in a sub-step
// store consecutive gpos; consecutive sub-steps append -> L2 write-combining.
__global__ __launch_bounds__(256) void partition_kernel(
        const float* __restrict__ w,
        const int*   __restrict__ src,
        const int*   __restrict__ dst,
        const int*   __restrict__ bases,
        int2* __restrict__ recs) {
    const int lane  = threadIdx.x & 63;
    const int wv    = threadIdx.x >> 6;
    const int chunk = blockIdx.x * PW + wv;
    if (chunk >= NCH) return;
    const unsigned long long ltmask = (1ull << lane) - 1ull;

    int cur = 0;                              // lane r<16 holds range r's cursor
    if (lane < RANGES) cur = bases[(size_t)lane * NCH + chunk];

    const int beg = chunk * CHK;
    const int4* dst4 = (const int4*)dst;
    const int4* src4 = (const int4*)src;
    const int4* wq4  = (const int4*)w;

    for (int it = 0; it < PITER; ++it) {
        int e   = beg + (it * 64 + lane) * 4;
        bool ok = (e < E_SYN);
        int idx = e >> 2;
        int4 d4 = ok ? dst4[idx] : make_int4(0, 0, 0, 0);
        int4 s4 = ok ? src4[idx] : make_int4(0, 0, 0, 0);
        int4 q4 = ok ? wq4[idx]  : make_int4(0, 0, 0, 0);
        unsigned long long okm = __ballot(ok);
        int dd[4] = {d4.x, d4.y, d4.z, d4.w};
        int ss[4] = {s4.x, s4.y, s4.z, s4.w};
        int qq[4] = {q4.x, q4.y, q4.z, q4.w};
#pragma unroll
        for (int k = 0; k < 4; ++k) {
            int d = dd[k];
            int r = d / BIN;
            unsigned long long b0 = __ballot(r & 1);
            unsigned long long b1 = __ballot(r & 2);
            unsigned long long b2 = __ballot(r & 4);
            unsigned long long b3 = __ballot(r & 8);
            unsigned long long mym = CMB(r, b0, b1, b2, b3) & okm;
            int rank = __popcll(mym & ltmask);
            int gpos = __shfl(cur, r, 64) + rank;
            if (ok) recs[(size_t)gpos] =
                make_int2((ss[k] << SHIFT) | (d - r * BIN), qq[k]);
            unsigned long long mm = CMB(lane, b0, b1, b2, b3) & okm;
            cur += __popcll(mm);
        }
    }
}

// Per step: block (r,c) streams a stripe of bucket r. 512 thr, 25KB bins ->
// 4 blocks/CU = 100% thread occupancy. 4 independent int4 loads hoisted
// ahead of all gathers/atomics for MLP (depth-4 keeps VGPR<=64 for 8 w/SIMD).
// partials layout is [stripe c][global neuron] -> reduce never straddles.
__global__ __launch_bounds__(SCAT_BLK) void scatter_sorted(
        const int2* __restrict__ recs,
        const int*  __restrict__ gcur,
        const float* __restrict__ v,
        float* __restrict__ partials) {
    __shared__ float bins[BIN];
    const int r = blockIdx.x / CBLK;
    const int c = blockIdx.x % CBLK;
    const int tid = threadIdx.x;
    for (int j = tid; j < BIN; j += SCAT_BLK) bins[j] = 0.0f;
    __syncthreads();

    const int cnt   = gcur[r];
    const int npair = cnt >> 1;
    const int4* base4 = (const int4*)(recs + (size_t)r * CAP);
    const int stride = CBLK * SCAT_BLK;
    int u = c * SCAT_BLK + tid;
    for (; u + 3 * stride < npair; u += 4 * stride) {
        int4 A[4];
#pragma unroll
        for (int i = 0; i < 4; ++i) A[i] = base4[u + i * stride];
        float g[8];
#pragma unroll
        for (int i = 0; i < 4; ++i) {
            g[2 * i]     = v[A[i].x >> SHIFT];
            g[2 * i + 1] = v[A[i].z >> SHIFT];
        }
#pragma unroll
        for (int i = 0; i < 4; ++i) {
            atomicAdd(&bins[A[i].x & DMASK], g[2 * i]     * __int_as_float(A[i].y));
            atomicAdd(&bins[A[i].z & DMASK], g[2 * i + 1] * __int_as_float(A[i].w));
        }
    }
    for (; u < npair; u += stride) {
        int4 a = base4[u];
        float v0 = v[a.x >> SHIFT];
        float v1 = v[a.z >> SHIFT];
        atomicAdd(&bins[a.x & DMASK], v0 * __int_as_float(a.y));
        atomicAdd(&bins[a.z & DMASK], v1 * __int_as_float(a.w));
    }
    if ((cnt & 1) && c == 0 && tid == 0) {
        int2 p = recs[(size_t)r * CAP + cnt - 1];
        atomicAdd(&bins[p.x & DMASK], v[p.x >> SHIFT] * __int_as_float(p.y));
    }
    __syncthreads();
    float* o = partials + (size_t)c * N_NEURONS + r * BIN;
    for (int j = tid; j < BIN; j += SCAT_BLK) o[j] = bins[j];
}

// Fused reduce over [stripe][global] partials: 64 stripes as 8 sequential
// groups of 8 (fixed association), then bias + tanh (except outputs).
// Aligned float4, no range straddling.
__global__ void reduce_fused(const float* __restrict__ partials,
                             const float* __restrict__ bias,
                             float* __restrict__ v,
                             float* __restrict__ out,
                             int write_out) {
    int i4 = 4 * (blockIdx.x * blockDim.x + threadIdx.x);
    if (i4 >= N_NEURONS) return;
    const float* base = partials + i4;
    float4 tot = {0.f, 0.f, 0.f, 0.f};
#pragma unroll 2
    for (int g = 0; g < RG; ++g) {
        float4 a = {0.f, 0.f, 0.f, 0.f};
#pragma unroll
        for (int cc = 0; cc < RSL; ++cc) {
            float4 p = *(const float4*)(base + (size_t)(g * RSL + cc) * N_NEURONS);
            a.x += p.x; a.y += p.y; a.z += p.z; a.w += p.w;
        }
        tot.x += a.x; tot.y += a.y; tot.z += a.z; tot.w += a.w;
    }
    float av[4] = {tot.x, tot.y, tot.z, tot.w};
#pragma unroll
    for (int k = 0; k < 4; ++k) {
        int i = i4 + k;
        float val = av[k] + ((i >= INPUT_SIZE) ? bias[i - INPUT_SIZE] : 0.0f);
        float nv  = (i < N_NEURONS - OUTPUT_SIZE) ? tanhf(val) : val;
        v[i] = nv;
        if (write_out && i >= N_NEURONS - OUTPUT_SIZE)
            out[i - (N_NEURONS - OUTPUT_SIZE)] = val;
    }
}

// ---- fallback (small ws): multi-pass binned rescan path ----
__global__ void init_state_fb(const float* __restrict__ x, float* __restrict__ v) {
    int i = blockIdx.x * blockDim.x + threadIdx.x;
    if (i < N_NEURONS) v[i] = (i < INPUT_SIZE) ? x[i] : 0.0f;
}
__global__ void scatter_binned(const float* __restrict__ w,
                               const int*   __restrict__ src,
                               const int*   __restrict__ dst,
                               const float* __restrict__ v,
                               float*       __restrict__ partials,
                               int C) {
    __shared__ float bins[BIN];
    const int r = blockIdx.x / C;
    const int c = blockIdx.x % C;
    const int lo = r * BIN;
    const int hi = lo + BIN;
    for (int j = threadIdx.x; j < BIN; j += blockDim.x) bins[j] = 0.0f;
    __syncthreads();
    const int4*   src4 = (const int4*)src;
    const int4*   dst4 = (const int4*)dst;
    const float4* w4v  = (const float4*)w;
    const int stride = C * blockDim.x;
    for (int u = c * blockDim.x + threadIdx.x; u < VEC4; u += stride) {
        const int4   s4 = src4[u];
        const int4   d4 = dst4[u];
        const float4 wv = w4v[u];
        int   s[4] = {s4.x, s4.y, s4.z, s4.w};
        int   d[4] = {d4.x, d4.y, d4.z, d4.w};
        float ww[4] = {wv.x, wv.y, wv.z, wv.w};
#pragma unroll
        for (int k = 0; k < 4; ++k)
            if (d[k] >= lo && d[k] < hi)
                atomicAdd(&bins[d[k] - lo], v[s[k]] * ww[k]);
    }
    __syncthreads();
    float* o = partials + (size_t)c * N_NEURONS + r * BIN;
    for (int j = threadIdx.x; j < BIN; j += blockDim.x) o[j] = bins[j];
}
__global__ void reduce_update_fb(const float* __restrict__ partials,
                                 const float* __restrict__ bias,
                                 float* __restrict__ v,
                                 float* __restrict__ out,
                                 int C, int write_out) {
    int i4 = 4 * (blockIdx.x * blockDim.x + threadIdx.x);
    if (i4 >= N_NEURONS) return;
    const float* base = partials + i4;
    float4 acc = {0.f, 0.f, 0.f, 0.f};
    for (int c = 0; c < C; ++c) {
        float4 p = *(const float4*)(base + (size_t)c * N_NEURONS);
        acc.x += p.x; acc.y += p.y; acc.z += p.z; acc.w += p.w;
    }
    float av[4] = {acc.x, acc.y, acc.z, acc.w};
#pragma unroll
    for (int k = 0; k < 4; ++k) {
        int i = i4 + k;
        float val = av[k] + ((i >= INPUT_SIZE) ? bias[i - INPUT_SIZE] : 0.0f);
        float nv  = (i < N_NEURONS - OUTPUT_SIZE) ? tanhf(val) : val;
        v[i] = nv;
        if (write_out && i >= N_NEURONS - OUTPUT_SIZE)
            out[i - (N_NEURONS - OUTPUT_SIZE)] = val;
    }
}

extern "C" void kernel_launch(void* const* d_in, const int* in_sizes, int n_in,
                              void* d_out, int out_size, void* d_ws, size_t ws_size,
                              hipStream_t stream) {
    const float* x    = (const float*)d_in[0];
    const float* w    = (const float*)d_in[1];
    const float* bias = (const float*)d_in[2];
    const int*   src  = (const int*)d_in[3];
    const int*   dst  = (const int*)d_in[4];
    float* out = (float*)d_out;

    const int blk = 256;
    const int grid_n   = (N_NEURONS + blk - 1) / blk;
    const int red_grid = (N_NEURONS / 4 + blk - 1) / blk;

    // ws layout: v | partials | hist | bases | gcur | recs
    float* v        = (float*)d_ws;
    float* partials = v + N_NEURONS;
    int*   hist     = (int*)(partials + (size_t)CBLK * N_NEURONS);
    int*   bases    = hist + (size_t)RANGES * NCH;
    int*   gcur     = bases + (size_t)RANGES * NCH;
    int2*  recs     = (int2*)(gcur + RANGES);
    size_t need = (size_t)((char*)(recs + (size_t)RANGES * CAP) - (char*)d_ws);

    if (ws_size >= need) {
        hist_kernel<<<HIST_GRID, 256, 0, stream>>>(x, v, dst, hist);
        scan_kernel<<<RANGES, 1024, 0, stream>>>(hist, bases, gcur);
        partition_kernel<<<HIST_GRID, 256, 0, stream>>>(w, src, dst, bases, recs);
        for (int s = 0; s < STEPS; ++s) {
            scatter_sorted<<<RANGES * CBLK, SCAT_BLK, 0, stream>>>(
                recs, gcur, v, partials);
            reduce_fused<<<red_grid, blk, 0, stream>>>(
                partials, bias, v, out, s == STEPS - 1 ? 1 : 0);
        }
    } else {
        long C = (long)(ws_size / 4 / N_NEURONS) - 1;
        if (C > 64) C = 64;
        if (C < 1) C = 1;
        float* part_fb = v + N_NEURONS;
        init_state_fb<<<grid_n, blk, 0, stream>>>(x, v);
        for (int s = 0; s < STEPS; ++s) {
            scatter_binned<<<RANGES * (int)C, SCAT_BLK, 0, stream>>>(
                w, src, dst, v, part_fb, (int)C);
            reduce_update_fb<<<red_grid, blk, 0, stream>>>(
                part_fb, bias, v, out, (int)C, s == STEPS - 1 ? 1 : 0);
        }
    }
}